// Round 4
// baseline (150.196 us; speedup 1.0000x reference)
//
#include <hip/hip_runtime.h>

// SPD loss: 18-bin (9 class x 2 group) histogram over 16.7M int32 pairs + tiny epilogue.
// R0: scattered LDS atomics -> 55 us.
// R1: register-packed histogram, same 55 us; warm==cold -> not LDS, not HBM.
// R2: removed global atomics -> 45 us, warm==cold at 1.4 TB/s: latency/MLP-bound.
// R3: "issue all 16 loads up front" in source — VGPR_Count=40: compiler re-serialized.
// R4: __launch_bounds__(512,4) permission — VGPR still 40. Permission != force.
// R5: inline-asm pin of 16 quads — VGPR only 48, dur 45us. Burst still not in ISA.
//     Macro-observation: occupancy 32% time-avg => avg wave lives ~35k cyc for
//     ~900 instrs: one-shot kernel (1 superiteration/thread) has NO steady state;
//     memory only loaded during staggered burst windows. 4.65 B/cyc/CU delivered
//     vs >10 sustained by m13/m146 kernels.
// R6: persistent software-pipelined kernel — NOT MEASURED (container acquire
//     failed twice; infra, not kernel). R7 = R6 resubmitted unchanged.
// R7 (this): grid 512 x block 512 (16 waves/CU), each thread: 4 iterations x
//     4 int4-pairs, TWO named register buffers. Issue next buffer's 8 loads,
//     then pin current buffer ("memory" clobber: next loads can't sink past)
//     -> waitcnt is vmcnt(8) in steady state, next buffer stays in flight while
//     consuming. Cross-wave + cross-iter overlap = steady state.
//     Predict: VGPR ~100-128, hist 45 -> 22-28 us, VALUBusy ~25-30%.
//     If VGPR rises but dur unchanged: conclude ~3 TB/s service cap for this
//     pattern, pivot to global_load_lds deep queue / nt cache modifiers.

#define N_CLASSES 9
#define N_GROUPS 2
#define NBINS (N_CLASSES * N_GROUPS)  // 18
#define BDIM 512
#define ITEMS 4                        // int4-pairs per inner iteration
#define NITER 4                        // pipelined inner iterations per outer step
#define SPAN (BDIM * ITEMS)            // int4s per block per inner iter  = 2048
#define BLOCKSPAN (SPAN * NITER)       // int4s per block per outer step  = 8192

typedef int vint4 __attribute__((ext_vector_type(4)));

__global__ __launch_bounds__(BDIM, 4) void spd_hist_kernel(
    const int* __restrict__ preds,
    const int* __restrict__ attrs,
    unsigned int* __restrict__ partials,  // [gridDim.x][NBINS]
    int n4, int n)
{
    __shared__ unsigned int lh0[N_CLASSES];
    __shared__ unsigned int lh1[N_CLASSES];
    if (threadIdx.x < N_CLASSES) { lh0[threadIdx.x] = 0u; lh1[threadIdx.x] = 0u; }
    __syncthreads();

    // per-thread 16-bit packed totals: lo16 = group0, hi16 = group1
    unsigned int cnt[N_CLASSES];
    #pragma unroll
    for (int p = 0; p < N_CLASSES; ++p) cnt[p] = 0u;

    const vint4* __restrict__ p4 = (const vint4*)preds;
    const vint4* __restrict__ a4 = (const vint4*)attrs;

    for (int S = blockIdx.x * BLOCKSPAN; S < n4; S += gridDim.x * BLOCKSPAN) {
        const int s = S + (int)threadIdx.x;
        // accT: per-class TOTAL count (7-bit fields, <=64 per field per outer step);
        // acc1: per-class group-1 count.
        unsigned long long accT = 0ull, acc1 = 0ull;

        if (S + BLOCKSPAN <= n4) {
            // ---- pipelined fast path: two named register buffers ----
            vint4 aP0, aP1, aP2, aP3, aA0, aA1, aA2, aA3;
            vint4 bP0, bP1, bP2, bP3, bA0, bA1, bA2, bA3;

            #define LDBUF(B, base) \
                B##P0 = p4[(base)];            B##A0 = a4[(base)]; \
                B##P1 = p4[(base) + BDIM];     B##A1 = a4[(base) + BDIM]; \
                B##P2 = p4[(base) + 2*BDIM];   B##A2 = a4[(base) + 2*BDIM]; \
                B##P3 = p4[(base) + 3*BDIM];   B##A3 = a4[(base) + 3*BDIM];

            // "memory" clobber: later loads in program order cannot be hoisted
            // above, earlier loads cannot be sunk below -> issue order pinned.
            // The implied waitcnt covers ONLY the pinned registers (vmcnt(8)
            // in steady state, other buffer's loads stay outstanding).
            #define PIN(B) asm volatile("" : \
                "+v"(B##P0), "+v"(B##P1), "+v"(B##P2), "+v"(B##P3), \
                "+v"(B##A0), "+v"(B##A1), "+v"(B##A2), "+v"(B##A3) :: "memory");

            #define CONS1(P, A) { \
                { unsigned long long inc = 1ull << (7 * P.x); accT += inc; acc1 += (A.x == 0) ? 0ull : inc; } \
                { unsigned long long inc = 1ull << (7 * P.y); accT += inc; acc1 += (A.y == 0) ? 0ull : inc; } \
                { unsigned long long inc = 1ull << (7 * P.z); accT += inc; acc1 += (A.z == 0) ? 0ull : inc; } \
                { unsigned long long inc = 1ull << (7 * P.w); accT += inc; acc1 += (A.w == 0) ? 0ull : inc; } \
            }
            #define CONSBUF(B) \
                CONS1(B##P0, B##A0) CONS1(B##P1, B##A1) \
                CONS1(B##P2, B##A2) CONS1(B##P3, B##A3)

            LDBUF(a, s)                    // iter 0 loads in flight
            LDBUF(b, s + SPAN)             // iter 1 loads in flight
            PIN(a) CONSBUF(a)              // wait iter0 only, consume
            LDBUF(a, s + 2 * SPAN)         // iter 2 loads in flight
            PIN(b) CONSBUF(b)              // wait iter1 only, consume
            LDBUF(b, s + 3 * SPAN)         // iter 3 loads in flight
            PIN(a) CONSBUF(a)              // wait iter2, consume
            PIN(b) CONSBUF(b)              // wait iter3, consume

            #undef LDBUF
            #undef PIN
            #undef CONS1
            #undef CONSBUF
        } else {
            // masked tail: same coverage (s + m*BDIM, m in [0, NITER*ITEMS))
            for (int m = 0; m < NITER * ITEMS; ++m) {
                const int idx = s + m * BDIM;
                if (idx < n4) {
                    vint4 pp = p4[idx];
                    vint4 aa = a4[idx];
                    {
                        unsigned long long inc = 1ull << (7 * pp.x);
                        accT += inc; acc1 += (aa.x == 0) ? 0ull : inc;
                    }
                    {
                        unsigned long long inc = 1ull << (7 * pp.y);
                        accT += inc; acc1 += (aa.y == 0) ? 0ull : inc;
                    }
                    {
                        unsigned long long inc = 1ull << (7 * pp.z);
                        accT += inc; acc1 += (aa.z == 0) ? 0ull : inc;
                    }
                    {
                        unsigned long long inc = 1ull << (7 * pp.w);
                        accT += inc; acc1 += (aa.w == 0) ? 0ull : inc;
                    }
                }
            }
        }

        // flush 7-bit windows (<=64 per field) into 16-bit packed totals.
        // group0 = total - group1.
        #pragma unroll
        for (int p = 0; p < N_CLASSES; ++p) {
            unsigned int ct = (unsigned int)(accT >> (7 * p)) & 127u;
            unsigned int c1 = (unsigned int)(acc1 >> (7 * p)) & 127u;
            cnt[p] += (ct - c1) | (c1 << 16);
        }
    }

    // scalar remainder (n % 4), block 0 only: <=3 items
    if (blockIdx.x == 0) {
        for (int t = n4 * 4 + (int)threadIdx.x; t < n; t += BDIM)
            cnt[preds[t]] += (attrs[t] == 0) ? 1u : 0x10000u;
    }

    // wave-64 butterfly; 16-bit halves stay far below 65536 for this N
    #pragma unroll
    for (int m = 1; m < 64; m <<= 1) {
        #pragma unroll
        for (int p = 0; p < N_CLASSES; ++p)
            cnt[p] += __shfl_xor(cnt[p], m, 64);
    }

    // wave leaders -> block LDS (u32 per group)
    if ((threadIdx.x & 63) == 0) {
        #pragma unroll
        for (int p = 0; p < N_CLASSES; ++p) {
            atomicAdd(&lh0[p], cnt[p] & 0xFFFFu);
            atomicAdd(&lh1[p], cnt[p] >> 16);
        }
    }
    __syncthreads();

    // plain stores — no global atomics
    if (threadIdx.x < NBINS) {
        int c = threadIdx.x >> 1;
        unsigned int v = (threadIdx.x & 1) ? lh1[c] : lh0[c];
        partials[blockIdx.x * NBINS + threadIdx.x] = v;
    }
}

__global__ __launch_bounds__(1024) void spd_finalize_kernel(
    const unsigned int* __restrict__ partials,
    float* __restrict__ out, int nblocks, double n_total)
{
    __shared__ double counts[NBINS];
    const int tid = threadIdx.x;

    if (tid < NBINS * 32) {
        const int bin = tid >> 5;
        const int j = tid & 31;
        unsigned int s = 0u;
        #pragma unroll 8
        for (int b = j; b < nblocks; b += 32)
            s += partials[b * NBINS + bin];
        #pragma unroll
        for (int m = 1; m < 32; m <<= 1)
            s += __shfl_xor(s, m, 32);
        if (j == 0) counts[bin] = (double)s;
    }
    __syncthreads();

    if (tid == 0) {
        double n1 = 0.0;
        #pragma unroll
        for (int c = 0; c < N_CLASSES; ++c)
            n1 += counts[c * N_GROUPS + 1];
        double n0 = n_total - n1;
        double acc = 0.0;
        #pragma unroll
        for (int c = 0; c < N_CLASSES; ++c) {
            double d = counts[c * N_GROUPS] / n0 - counts[c * N_GROUPS + 1] / n1;
            acc += d * d;
        }
        out[0] = (float)acc;
    }
}

extern "C" void kernel_launch(void* const* d_in, const int* in_sizes, int n_in,
                              void* d_out, int out_size, void* d_ws, size_t ws_size,
                              hipStream_t stream)
{
    const int* preds = (const int*)d_in[0];
    const int* attrs = (const int*)d_in[1];
    const int n = in_sizes[0];

    unsigned int* partials = (unsigned int*)d_ws;

    const int n4 = n / 4;
    int grid = (n4 + BLOCKSPAN - 1) / BLOCKSPAN;      // 512 for N=16.7M
    if (grid > 1024) grid = 1024;
    int max_grid = (int)(ws_size / (NBINS * sizeof(unsigned int)));
    if (grid > max_grid) grid = max_grid;
    if (grid < 1) grid = 1;

    spd_hist_kernel<<<grid, BDIM, 0, stream>>>(preds, attrs, partials, n4, n);
    spd_finalize_kernel<<<1, 1024, 0, stream>>>(partials, (float*)d_out, grid, (double)n);
}

// Round 5
// 149.638 us; speedup vs baseline: 1.0037x; 1.0037x over previous
//
#include <hip/hip_runtime.h>

// SPD loss: 18-bin (9 class x 2 group) histogram over 16.7M int32 pairs + tiny epilogue.
// R0: scattered LDS atomics -> 55 us.
// R1: register-packed histogram, same 55 us; warm==cold -> not LDS, not HBM.
// R2: removed global atomics -> 45 us, warm==cold at 1.4 TB/s HBM (2.95 TB/s delivered).
// R3: source-level 16-load burst — VGPR_Count=40: compiler re-serialized.
// R4: __launch_bounds__(512,4) — VGPR still 40. Permission != force.
// R5: asm pin of 16 quads — VGPR 48, dur 45us. Burst not in ISA.
// R7: 2-deep pinned double-buffer — VGPR 44 (!cannot hold 64 live), dur 45us.
//     HIP-level liveness tricks are all undone by the backend.
// R8 (this): loads emitted IN inline asm — 16x global_load_dwordx4 (8 pred + 8
//     attr interleaved), then 8 consume stages gated by s_waitcnt vmcnt(14-2k)
//     + sched_barrier(0) (guide rule #18). Compiler cannot sink/split/re-wait.
//     DECISIVE: (a) if request-side MLP was the limit -> hist 22-30us;
//     (b) if the ~3.1 TB/s read-path ceiling is real (m13 copy = 3.15 TB/s
//     read; all 6 variants cap at 2.95; warm==cold) -> hist stays 44-46us
//     with VGPR>=90, and 134MB/3.15TB/s = 42.6us IS the roofline.

#define N_CLASSES 9
#define N_GROUPS 2
#define NBINS (N_CLASSES * N_GROUPS)  // 18
#define BDIM 512
#define ITEMS 8                        // int4-PAIRS per thread (8 pred + 8 attr int4 loads)
#define BLOCKSPAN (BDIM * ITEMS)       // int4s per block per outer step = 4096

typedef int vint4 __attribute__((ext_vector_type(4)));

__global__ __launch_bounds__(BDIM, 2) void spd_hist_kernel(
    const int* __restrict__ preds,
    const int* __restrict__ attrs,
    unsigned int* __restrict__ partials,  // [gridDim.x][NBINS]
    int n4, int n)
{
    __shared__ unsigned int lh0[N_CLASSES];
    __shared__ unsigned int lh1[N_CLASSES];
    if (threadIdx.x < N_CLASSES) { lh0[threadIdx.x] = 0u; lh1[threadIdx.x] = 0u; }
    __syncthreads();

    // per-thread 16-bit packed totals: lo16 = group0, hi16 = group1
    unsigned int cnt[N_CLASSES];
    #pragma unroll
    for (int p = 0; p < N_CLASSES; ++p) cnt[p] = 0u;

    const vint4* __restrict__ p4 = (const vint4*)preds;
    const vint4* __restrict__ a4 = (const vint4*)attrs;

    for (int S = blockIdx.x * BLOCKSPAN; S < n4; S += gridDim.x * BLOCKSPAN) {
        // accT: per-class TOTAL count (7-bit fields, <=32 per field per step);
        // acc1: per-class group-1 count.
        unsigned long long accT = 0ull, acc1 = 0ull;

        if (S + BLOCKSPAN <= n4) {
            // ---- asm-issued deep load pipeline ----
            // byte offsets for k=0..7 relative to the (uniform) array bases
            unsigned int off0 = ((unsigned int)(S + (int)threadIdx.x)) * 16u;
            unsigned int o0 = off0;
            unsigned int o1 = off0 + 1u * BDIM * 16u;
            unsigned int o2 = off0 + 2u * BDIM * 16u;
            unsigned int o3 = off0 + 3u * BDIM * 16u;
            unsigned int o4 = off0 + 4u * BDIM * 16u;
            unsigned int o5 = off0 + 5u * BDIM * 16u;
            unsigned int o6 = off0 + 6u * BDIM * 16u;
            unsigned int o7 = off0 + 7u * BDIM * 16u;

            vint4 P0, P1, P2, P3, P4, P5, P6, P7;
            vint4 A0, A1, A2, A3, A4, A5, A6, A7;

            // 16 loads issued back-to-back, interleaved p,a,p,a,... so that
            // pair k is complete when vmcnt <= 14-2k. Compiler cannot touch.
            asm volatile(
                "global_load_dwordx4 %0, %16, %24\n\t"
                "global_load_dwordx4 %8, %16, %25\n\t"
                "global_load_dwordx4 %1, %17, %24\n\t"
                "global_load_dwordx4 %9, %17, %25\n\t"
                "global_load_dwordx4 %2, %18, %24\n\t"
                "global_load_dwordx4 %10, %18, %25\n\t"
                "global_load_dwordx4 %3, %19, %24\n\t"
                "global_load_dwordx4 %11, %19, %25\n\t"
                "global_load_dwordx4 %4, %20, %24\n\t"
                "global_load_dwordx4 %12, %20, %25\n\t"
                "global_load_dwordx4 %5, %21, %24\n\t"
                "global_load_dwordx4 %13, %21, %25\n\t"
                "global_load_dwordx4 %6, %22, %24\n\t"
                "global_load_dwordx4 %14, %22, %25\n\t"
                "global_load_dwordx4 %7, %23, %24\n\t"
                "global_load_dwordx4 %15, %23, %25"
                : "=&v"(P0), "=&v"(P1), "=&v"(P2), "=&v"(P3),
                  "=&v"(P4), "=&v"(P5), "=&v"(P6), "=&v"(P7),
                  "=&v"(A0), "=&v"(A1), "=&v"(A2), "=&v"(A3),
                  "=&v"(A4), "=&v"(A5), "=&v"(A6), "=&v"(A7)
                : "v"(o0), "v"(o1), "v"(o2), "v"(o3),
                  "v"(o4), "v"(o5), "v"(o6), "v"(o7),
                  "s"(preds), "s"(attrs));

            #define CONS1(P, A) { \
                { unsigned long long inc = 1ull << (7 * P.x); accT += inc; acc1 += (A.x == 0) ? 0ull : inc; } \
                { unsigned long long inc = 1ull << (7 * P.y); accT += inc; acc1 += (A.y == 0) ? 0ull : inc; } \
                { unsigned long long inc = 1ull << (7 * P.z); accT += inc; acc1 += (A.z == 0) ? 0ull : inc; } \
                { unsigned long long inc = 1ull << (7 * P.w); accT += inc; acc1 += (A.w == 0) ? 0ull : inc; } \
            }
            // consume stage k: wait only for the 2(k+1) oldest loads; the rest
            // stay in flight. sched_barrier(0) per guide rule #18 (compiler
            // hoists register-only ops past inline-asm waitcnt otherwise).
            #define STAGE(k, VM) \
                asm volatile("s_waitcnt vmcnt(" #VM ")"); \
                __builtin_amdgcn_sched_barrier(0); \
                CONS1(P##k, A##k)

            STAGE(0, 14) STAGE(1, 12) STAGE(2, 10) STAGE(3, 8)
            STAGE(4, 6)  STAGE(5, 4)  STAGE(6, 2)  STAGE(7, 0)
            #undef STAGE
            #undef CONS1
        } else {
            // masked tail: same coverage (s + m*BDIM, m in [0, ITEMS))
            const int s = S + (int)threadIdx.x;
            for (int m = 0; m < ITEMS; ++m) {
                const int idx = s + m * BDIM;
                if (idx < n4) {
                    vint4 pp = p4[idx];
                    vint4 aa = a4[idx];
                    {
                        unsigned long long inc = 1ull << (7 * pp.x);
                        accT += inc; acc1 += (aa.x == 0) ? 0ull : inc;
                    }
                    {
                        unsigned long long inc = 1ull << (7 * pp.y);
                        accT += inc; acc1 += (aa.y == 0) ? 0ull : inc;
                    }
                    {
                        unsigned long long inc = 1ull << (7 * pp.z);
                        accT += inc; acc1 += (aa.z == 0) ? 0ull : inc;
                    }
                    {
                        unsigned long long inc = 1ull << (7 * pp.w);
                        accT += inc; acc1 += (aa.w == 0) ? 0ull : inc;
                    }
                }
            }
        }

        // flush 7-bit windows (<=32 per field) into 16-bit packed totals.
        // group0 = total - group1.
        #pragma unroll
        for (int p = 0; p < N_CLASSES; ++p) {
            unsigned int ct = (unsigned int)(accT >> (7 * p)) & 127u;
            unsigned int c1 = (unsigned int)(acc1 >> (7 * p)) & 127u;
            cnt[p] += (ct - c1) | (c1 << 16);
        }
    }

    // scalar remainder (n % 4), block 0 only: <=3 items
    if (blockIdx.x == 0) {
        for (int t = n4 * 4 + (int)threadIdx.x; t < n; t += BDIM)
            cnt[preds[t]] += (attrs[t] == 0) ? 1u : 0x10000u;
    }

    // wave-64 butterfly; 16-bit halves stay far below 65536 for this N
    #pragma unroll
    for (int m = 1; m < 64; m <<= 1) {
        #pragma unroll
        for (int p = 0; p < N_CLASSES; ++p)
            cnt[p] += __shfl_xor(cnt[p], m, 64);
    }

    // wave leaders -> block LDS (u32 per group)
    if ((threadIdx.x & 63) == 0) {
        #pragma unroll
        for (int p = 0; p < N_CLASSES; ++p) {
            atomicAdd(&lh0[p], cnt[p] & 0xFFFFu);
            atomicAdd(&lh1[p], cnt[p] >> 16);
        }
    }
    __syncthreads();

    // plain stores — no global atomics
    if (threadIdx.x < NBINS) {
        int c = threadIdx.x >> 1;
        unsigned int v = (threadIdx.x & 1) ? lh1[c] : lh0[c];
        partials[blockIdx.x * NBINS + threadIdx.x] = v;
    }
}

__global__ __launch_bounds__(1024) void spd_finalize_kernel(
    const unsigned int* __restrict__ partials,
    float* __restrict__ out, int nblocks, double n_total)
{
    __shared__ double counts[NBINS];
    const int tid = threadIdx.x;

    if (tid < NBINS * 32) {
        const int bin = tid >> 5;
        const int j = tid & 31;
        unsigned int s = 0u;
        #pragma unroll 8
        for (int b = j; b < nblocks; b += 32)
            s += partials[b * NBINS + bin];
        #pragma unroll
        for (int m = 1; m < 32; m <<= 1)
            s += __shfl_xor(s, m, 32);
        if (j == 0) counts[bin] = (double)s;
    }
    __syncthreads();

    if (tid == 0) {
        double n1 = 0.0;
        #pragma unroll
        for (int c = 0; c < N_CLASSES; ++c)
            n1 += counts[c * N_GROUPS + 1];
        double n0 = n_total - n1;
        double acc = 0.0;
        #pragma unroll
        for (int c = 0; c < N_CLASSES; ++c) {
            double d = counts[c * N_GROUPS] / n0 - counts[c * N_GROUPS + 1] / n1;
            acc += d * d;
        }
        out[0] = (float)acc;
    }
}

extern "C" void kernel_launch(void* const* d_in, const int* in_sizes, int n_in,
                              void* d_out, int out_size, void* d_ws, size_t ws_size,
                              hipStream_t stream)
{
    const int* preds = (const int*)d_in[0];
    const int* attrs = (const int*)d_in[1];
    const int n = in_sizes[0];

    unsigned int* partials = (unsigned int*)d_ws;

    const int n4 = n / 4;
    int grid = (n4 + BLOCKSPAN - 1) / BLOCKSPAN;      // 1024 for N=16.7M
    if (grid > 2048) grid = 2048;
    int max_grid = (int)(ws_size / (NBINS * sizeof(unsigned int)));
    if (grid > max_grid) grid = max_grid;
    if (grid < 1) grid = 1;

    spd_hist_kernel<<<grid, BDIM, 0, stream>>>(preds, attrs, partials, n4, n);
    spd_finalize_kernel<<<1, 1024, 0, stream>>>(partials, (float*)d_out, grid, (double)n);
}